// Round 1
// baseline (1651.062 us; speedup 1.0000x reference)
//
#include <hip/hip_runtime.h>
#include <math.h>

#define NH 16
#define HDIM 64
#define D_ATTN 1024
#define KW 4
#define ATT_SCALE 0.125f
#define LKV_C 512
#define LQ_C 4096
#define B_C 4

// C[M,N] = A[M,K] @ W[N,K]^T   (both row-major, K contiguous) — fp32 baseline
template<int BM, int BN, int BK>
__global__ __launch_bounds__(256) void gemm_nt(const float* __restrict__ A,
                                               const float* __restrict__ W,
                                               float* __restrict__ C,
                                               int M, int N, int K) {
    __shared__ float As[BK][BM + 1];
    __shared__ float Ws[BK][BN + 1];
    const int bm = blockIdx.y * BM;
    const int bn = blockIdx.x * BN;
    const int t = threadIdx.x;            // 256 threads
    const int tn = t % 16;                // 16x16 thread grid, 4x4 micro-tile
    const int tm = t / 16;

    float acc[4][4] = {};

    const int lrow = t / 4;               // 0..63
    const int lcol = (t % 4) * 4;         // 0,4,8,12

    for (int k0 = 0; k0 < K; k0 += BK) {
        float4 a4 = *(const float4*)(A + (size_t)(bm + lrow) * K + k0 + lcol);
        float4 w4 = *(const float4*)(W + (size_t)(bn + lrow) * K + k0 + lcol);
        As[lcol + 0][lrow] = a4.x; As[lcol + 1][lrow] = a4.y;
        As[lcol + 2][lrow] = a4.z; As[lcol + 3][lrow] = a4.w;
        Ws[lcol + 0][lrow] = w4.x; Ws[lcol + 1][lrow] = w4.y;
        Ws[lcol + 2][lrow] = w4.z; Ws[lcol + 3][lrow] = w4.w;
        __syncthreads();

        #pragma unroll
        for (int k = 0; k < BK; ++k) {
            float a[4], b[4];
            #pragma unroll
            for (int i = 0; i < 4; ++i) a[i] = As[k][tm * 4 + i];
            #pragma unroll
            for (int j = 0; j < 4; ++j) b[j] = Ws[k][tn * 4 + j];
            #pragma unroll
            for (int i = 0; i < 4; ++i)
                #pragma unroll
                for (int j = 0; j < 4; ++j)
                    acc[i][j] = fmaf(a[i], b[j], acc[i][j]);
        }
        __syncthreads();
    }

    #pragma unroll
    for (int i = 0; i < 4; ++i) {
        #pragma unroll
        for (int j = 0; j < 4; ++j) {
            C[(size_t)(bm + tm * 4 + i) * N + bn + tn * 4 + j] = acc[i][j];
        }
    }
}

// One wave (64 lanes) per (row, head). lane = d within the head.
__global__ __launch_bounds__(256) void attn_kernel(const float* __restrict__ qh,   // (B*LQ, 1024)
                                                   const float* __restrict__ kvp,  // (B*LKV, 2048): K|V
                                                   const int* __restrict__ seg_id, // (B*LQ)
                                                   float* __restrict__ out) {      // (B*LQ, 1024)
    const int wave = (blockIdx.x * blockDim.x + threadIdx.x) >> 6;
    const int lane = threadIdx.x & 63;
    const int h = wave % NH;
    const int row = wave / NH;            // b*LQ + qi
    const int b = row / LQ_C;
    const int seg = seg_id[row];

    const float qv = qh[(size_t)row * D_ATTN + h * HDIM + lane];

    float scores[KW];
    #pragma unroll
    for (int w = 0; w < KW; ++w) {
        const int j = seg - w;
        if (j >= 0) {
            float p = qv * kvp[(size_t)(b * LKV_C + j) * (2 * D_ATTN) + h * HDIM + lane];
            #pragma unroll
            for (int off = 32; off >= 1; off >>= 1) p += __shfl_xor(p, off, 64);
            scores[w] = p * ATT_SCALE;
        } else {
            scores[w] = -INFINITY;
        }
    }

    float m = scores[0];
    #pragma unroll
    for (int w = 1; w < KW; ++w) m = fmaxf(m, scores[w]);
    float e[KW], sum = 0.f;
    #pragma unroll
    for (int w = 0; w < KW; ++w) {
        e[w] = (scores[w] == -INFINITY) ? 0.f : expf(scores[w] - m);
        sum += e[w];
    }
    const float inv = 1.f / sum;

    float o = 0.f;
    #pragma unroll
    for (int w = 0; w < KW; ++w) {
        const int j = seg - w;
        if (j >= 0) {
            const float vd = kvp[(size_t)(b * LKV_C + j) * (2 * D_ATTN) + D_ATTN + h * HDIM + lane];
            o = fmaf(e[w] * inv, vd, o);
        }
    }
    out[(size_t)row * D_ATTN + h * HDIM + lane] = o;
}

extern "C" void kernel_launch(void* const* d_in, const int* in_sizes, int n_in,
                              void* d_out, int out_size, void* d_ws, size_t ws_size,
                              hipStream_t stream) {
    const float* q      = (const float*)d_in[0]; // (4,4096,1024)
    const float* kv_src = (const float*)d_in[1]; // (4,512,1024)
    const int*   seg    = (const int*)  d_in[2]; // (4,4096)
    const float* Wq     = (const float*)d_in[3]; // (1024,1024)
    const float* Wkv    = (const float*)d_in[4]; // (2048,1024)
    const float* Wo     = (const float*)d_in[5]; // (1024,1024)
    float* out = (float*)d_out;

    const int M  = B_C * LQ_C;    // 16384
    const int Mk = B_C * LKV_C;   // 2048

    float* qh   = (float*)d_ws;                       // 16384x1024  (64 MB)
    float* kvp  = qh  + (size_t)M * D_ATTN;           // 2048x2048   (16 MB)
    float* attn = kvp + (size_t)Mk * 2 * D_ATTN;      // 16384x1024  (64 MB)

    dim3 blk(256);

    // qh = q @ Wq^T
    gemm_nt<64, 64, 16><<<dim3(D_ATTN / 64, M / 64), blk, 0, stream>>>(q, Wq, qh, M, D_ATTN, 1024);
    // kv = kv_src @ Wkv^T
    gemm_nt<64, 64, 16><<<dim3(2 * D_ATTN / 64, Mk / 64), blk, 0, stream>>>(kv_src, Wkv, kvp, Mk, 2 * D_ATTN, 1024);
    // windowed attention
    attn_kernel<<<(M * NH) / 4, 256, 0, stream>>>(qh, kvp, seg, attn);
    // out = attn @ Wo^T
    gemm_nt<64, 64, 16><<<dim3(D_ATTN / 64, M / 64), blk, 0, stream>>>(attn, Wo, out, M, D_ATTN, 1024);
}

// Round 2
// 520.078 us; speedup vs baseline: 3.1746x; 3.1746x over previous
//
#include <hip/hip_runtime.h>
#include <math.h>

#define NH 16
#define HDIM 64
#define D_ATTN 1024
#define KW 4
#define ATT_SCALE 0.125f
#define LKV_C 512
#define LQ_C 4096
#define B_C 4

typedef unsigned short ushort_t;
typedef short bf16x8 __attribute__((ext_vector_type(8)));
typedef float f32x4 __attribute__((ext_vector_type(4)));

typedef __attribute__((address_space(3))) unsigned int as3_uint;
typedef __attribute__((address_space(1))) const unsigned int as1_uint;

__device__ __forceinline__ unsigned short f2bf_rne(float f) {
    unsigned u = __float_as_uint(f);
    unsigned r = u + 0x7fffu + ((u >> 16) & 1u);
    return (unsigned short)(r >> 16);
}

__device__ __forceinline__ void gld_lds16(const ushort_t* g, ushort_t* l) {
    __builtin_amdgcn_global_load_lds((as1_uint*)g, (as3_uint*)l, 16, 0, 0);
}

// fp32 -> (hi, lo) bf16 planes, round-to-nearest-even both stages.
__global__ __launch_bounds__(256) void split_kernel(const float* __restrict__ x,
                                                    ushort_t* __restrict__ hi,
                                                    ushort_t* __restrict__ lo, int n4) {
    int i = blockIdx.x * 256 + threadIdx.x;
    if (i >= n4) return;
    float4 v = ((const float4*)x)[i];
    float f[4] = {v.x, v.y, v.z, v.w};
    unsigned short h[4], l[4];
    #pragma unroll
    for (int j = 0; j < 4; ++j) {
        h[j] = f2bf_rne(f[j]);
        float hf = __uint_as_float((unsigned)h[j] << 16);
        l[j] = f2bf_rne(f[j] - hf);
    }
    ((ushort4*)hi)[i] = make_ushort4(h[0], h[1], h[2], h[3]);
    ((ushort4*)lo)[i] = make_ushort4(l[0], l[1], l[2], l[3]);
}

// C[M,N] = (Ahi+Alo)[M,K] @ (Whi+Wlo)[N,K]^T via 3-term split-bf16 MFMA.
// 128x128 tile, BK=32, 4 waves, each wave a 64x64 quadrant (4x4 grid of 16x16x32 MFMA).
__global__ __launch_bounds__(256) void gemm_split(const ushort_t* __restrict__ Ahi,
                                                  const ushort_t* __restrict__ Alo,
                                                  const ushort_t* __restrict__ Whi,
                                                  const ushort_t* __restrict__ Wlo,
                                                  float* __restrict__ C,
                                                  int M, int N, int K) {
    __shared__ ushort_t smem[4 * 128 * 32];   // Ahi | Alo | Bhi | Blo, 32 KB
    ushort_t* sAhi = smem;
    ushort_t* sAlo = smem + 4096;
    ushort_t* sBhi = smem + 8192;
    ushort_t* sBlo = smem + 12288;

    const int t = threadIdx.x;
    const int w = t >> 6;
    const int lane = t & 63;
    const int bm = blockIdx.y * 128;
    const int bn = blockIdx.x * 128;
    const int wm = (w & 1) * 64;
    const int wn = (w >> 1) * 64;

    f32x4 acc[4][4] = {};

    // fragment addressing: A[m = lane&15][k = (lane>>4)*8 + j]
    const int frow = lane & 15;
    const int fk = (lane >> 4) * 8;

    // staging addressing: flat = qi*256 + t; row = flat>>2; chunk = (flat&3)*8
    const int row0 = t >> 2,          ch0 = (t & 3) * 8;
    const int row1 = (256 + t) >> 2,  ch1 = (t & 3) * 8;   // (256+t)&3 == t&3
    const size_t aoff0 = (size_t)(bm + row0) * K + ch0;
    const size_t aoff1 = (size_t)(bm + row1) * K + ch1;
    const size_t boff0 = (size_t)(bn + row0) * K + ch0;
    const size_t boff1 = (size_t)(bn + row1) * K + ch1;
    const unsigned loff0 = (0 * 256 + w * 64) * 8;  // elements
    const unsigned loff1 = (1 * 256 + w * 64) * 8;

    // prologue: stage k0 = 0
    gld_lds16(Ahi + aoff0, sAhi + loff0);  gld_lds16(Ahi + aoff1, sAhi + loff1);
    gld_lds16(Alo + aoff0, sAlo + loff0);  gld_lds16(Alo + aoff1, sAlo + loff1);
    gld_lds16(Whi + boff0, sBhi + loff0);  gld_lds16(Whi + boff1, sBhi + loff1);
    gld_lds16(Wlo + boff0, sBlo + loff0);  gld_lds16(Wlo + boff1, sBlo + loff1);

    for (int k0 = 0; k0 < K; k0 += 32) {
        __syncthreads();   // staging of tile k0 complete (vmcnt drain at barrier)

        bf16x8 ahi[4], alo[4], bhi[4], blo[4];
        #pragma unroll
        for (int i = 0; i < 4; ++i) {
            const int r = (wm + i * 16 + frow) * 32 + fk;
            ahi[i] = *(const bf16x8*)(sAhi + r);
            alo[i] = *(const bf16x8*)(sAlo + r);
        }
        #pragma unroll
        for (int j = 0; j < 4; ++j) {
            const int r = (wn + j * 16 + frow) * 32 + fk;
            bhi[j] = *(const bf16x8*)(sBhi + r);
            blo[j] = *(const bf16x8*)(sBlo + r);
        }

        __syncthreads();   // all waves done reading LDS -> safe to overwrite

        if (k0 + 32 < K) { // stage next tile; async, overlaps the MFMAs below
            const int knext = k0 + 32;
            gld_lds16(Ahi + aoff0 + knext, sAhi + loff0);  gld_lds16(Ahi + aoff1 + knext, sAhi + loff1);
            gld_lds16(Alo + aoff0 + knext, sAlo + loff0);  gld_lds16(Alo + aoff1 + knext, sAlo + loff1);
            gld_lds16(Whi + boff0 + knext, sBhi + loff0);  gld_lds16(Whi + boff1 + knext, sBhi + loff1);
            gld_lds16(Wlo + boff0 + knext, sBlo + loff0);  gld_lds16(Wlo + boff1 + knext, sBlo + loff1);
        }

        #pragma unroll
        for (int i = 0; i < 4; ++i) {
            #pragma unroll
            for (int j = 0; j < 4; ++j) {
                acc[i][j] = __builtin_amdgcn_mfma_f32_16x16x32_bf16(ahi[i], bhi[j], acc[i][j], 0, 0, 0);
                acc[i][j] = __builtin_amdgcn_mfma_f32_16x16x32_bf16(ahi[i], blo[j], acc[i][j], 0, 0, 0);
                acc[i][j] = __builtin_amdgcn_mfma_f32_16x16x32_bf16(alo[i], bhi[j], acc[i][j], 0, 0, 0);
            }
        }
    }

    // epilogue: C/D layout col = lane&15, row = (lane>>4)*4 + reg
    const int rbase = bm + wm + (lane >> 4) * 4;
    const int cbase = bn + wn + (lane & 15);
    #pragma unroll
    for (int i = 0; i < 4; ++i)
        #pragma unroll
        for (int j = 0; j < 4; ++j)
            #pragma unroll
            for (int r = 0; r < 4; ++r)
                C[(size_t)(rbase + i * 16 + r) * N + cbase + j * 16] = acc[i][j][r];
}

// One wave per (row, head). lane = d within the head. Writes bf16 hi/lo planes.
__global__ __launch_bounds__(256) void attn_kernel(const float* __restrict__ qh,   // (B*LQ, 1024)
                                                   const float* __restrict__ kvp,  // (B*LKV, 2048): K|V
                                                   const int* __restrict__ seg_id, // (B*LQ)
                                                   ushort_t* __restrict__ ohi,
                                                   ushort_t* __restrict__ olo) {
    const int wave = (blockIdx.x * blockDim.x + threadIdx.x) >> 6;
    const int lane = threadIdx.x & 63;
    const int hd = wave % NH;
    const int row = wave / NH;            // b*LQ + qi
    const int b = row / LQ_C;
    const int seg = seg_id[row];

    const float qv = qh[(size_t)row * D_ATTN + hd * HDIM + lane];

    float scores[KW];
    #pragma unroll
    for (int w = 0; w < KW; ++w) {
        const int j = seg - w;
        if (j >= 0) {
            float p = qv * kvp[(size_t)(b * LKV_C + j) * (2 * D_ATTN) + hd * HDIM + lane];
            #pragma unroll
            for (int off = 32; off >= 1; off >>= 1) p += __shfl_xor(p, off, 64);
            scores[w] = p * ATT_SCALE;
        } else {
            scores[w] = -INFINITY;
        }
    }

    float m = scores[0];
    #pragma unroll
    for (int w = 1; w < KW; ++w) m = fmaxf(m, scores[w]);
    float e[KW], sum = 0.f;
    #pragma unroll
    for (int w = 0; w < KW; ++w) {
        e[w] = (scores[w] == -INFINITY) ? 0.f : expf(scores[w] - m);
        sum += e[w];
    }
    const float inv = 1.f / sum;

    float o = 0.f;
    #pragma unroll
    for (int w = 0; w < KW; ++w) {
        const int j = seg - w;
        if (j >= 0) {
            const float vd = kvp[(size_t)(b * LKV_C + j) * (2 * D_ATTN) + D_ATTN + hd * HDIM + lane];
            o = fmaf(e[w] * inv, vd, o);
        }
    }

    const unsigned short h = f2bf_rne(o);
    const float hf = __uint_as_float((unsigned)h << 16);
    const unsigned short l = f2bf_rne(o - hf);
    const size_t idx = (size_t)row * D_ATTN + hd * HDIM + lane;
    ohi[idx] = h;
    olo[idx] = l;
}

extern "C" void kernel_launch(void* const* d_in, const int* in_sizes, int n_in,
                              void* d_out, int out_size, void* d_ws, size_t ws_size,
                              hipStream_t stream) {
    const float* q      = (const float*)d_in[0]; // (4,4096,1024)
    const float* kv_src = (const float*)d_in[1]; // (4,512,1024)
    const int*   seg    = (const int*)  d_in[2]; // (4,4096)
    const float* Wq     = (const float*)d_in[3]; // (1024,1024)
    const float* Wkv    = (const float*)d_in[4]; // (2048,1024)
    const float* Wo     = (const float*)d_in[5]; // (1024,1024)
    float* out = (float*)d_out;

    const int M  = B_C * LQ_C;    // 16384
    const int Mk = B_C * LKV_C;   // 2048

    // workspace layout (104 MB total)
    ushort_t* q_hi   = (ushort_t*)d_ws;                  // 32 MB
    ushort_t* q_lo   = q_hi   + (size_t)M * D_ATTN;      // 32 MB
    ushort_t* kvs_hi = q_lo   + (size_t)M * D_ATTN;      // 4 MB
    ushort_t* kvs_lo = kvs_hi + (size_t)Mk * 1024;       // 4 MB
    ushort_t* Wq_hi  = kvs_lo + (size_t)Mk * 1024;       // 2 MB
    ushort_t* Wq_lo  = Wq_hi  + 1024 * 1024;             // 2 MB
    ushort_t* Wkv_hi = Wq_lo  + 1024 * 1024;             // 4 MB
    ushort_t* Wkv_lo = Wkv_hi + 2048 * 1024;             // 4 MB
    ushort_t* Wo_hi  = Wkv_lo + 2048 * 1024;             // 2 MB
    ushort_t* Wo_lo  = Wo_hi  + 1024 * 1024;             // 2 MB
    float*    kvp    = (float*)(Wo_lo + 1024 * 1024);    // 16 MB
    // attn hi/lo alias q hi/lo (q is dead after GEMM1); qh lives in d_out
    ushort_t* attn_hi = q_hi;
    ushort_t* attn_lo = q_lo;
    float*    qh = (float*)d_out;

    // 1. split fp32 inputs into bf16 hi/lo planes
    split_kernel<<<(M * D_ATTN) / 1024, 256, 0, stream>>>(q, q_hi, q_lo, (M * D_ATTN) / 4);
    split_kernel<<<(Mk * 1024) / 1024, 256, 0, stream>>>(kv_src, kvs_hi, kvs_lo, (Mk * 1024) / 4);
    split_kernel<<<(1024 * 1024) / 1024, 256, 0, stream>>>(Wq, Wq_hi, Wq_lo, (1024 * 1024) / 4);
    split_kernel<<<(2048 * 1024) / 1024, 256, 0, stream>>>(Wkv, Wkv_hi, Wkv_lo, (2048 * 1024) / 4);
    split_kernel<<<(1024 * 1024) / 1024, 256, 0, stream>>>(Wo, Wo_hi, Wo_lo, (1024 * 1024) / 4);

    // 2. qh = q @ Wq^T   (written into d_out; consumed by attention)
    gemm_split<<<dim3(1024 / 128, M / 128), 256, 0, stream>>>(q_hi, q_lo, Wq_hi, Wq_lo, qh, M, 1024, 1024);
    // 3. kvp = kv_src @ Wkv^T
    gemm_split<<<dim3(2048 / 128, Mk / 128), 256, 0, stream>>>(kvs_hi, kvs_lo, Wkv_hi, Wkv_lo, kvp, Mk, 2048, 1024);
    // 4. windowed attention -> attn hi/lo bf16 planes
    attn_kernel<<<(M * NH) / 4, 256, 0, stream>>>(qh, kvp, seg, attn_hi, attn_lo);
    // 5. out = attn @ Wo^T  (overwrites d_out)
    gemm_split<<<dim3(1024 / 128, M / 128), 256, 0, stream>>>(attn_hi, attn_lo, Wo_hi, Wo_lo, out, M, 1024, 1024);
}

// Round 3
// 369.233 us; speedup vs baseline: 4.4716x; 1.4085x over previous
//
#include <hip/hip_runtime.h>
#include <math.h>

#define NH 16
#define HDIM 64
#define D_ATTN 1024
#define KW 4
#define ATT_SCALE 0.125f
#define LKV_C 512
#define LQ_C 4096
#define B_C 4

typedef _Float16 f16;
typedef _Float16 f16x8 __attribute__((ext_vector_type(8)));
typedef _Float16 f16x4 __attribute__((ext_vector_type(4)));
typedef float f32x4 __attribute__((ext_vector_type(4)));

typedef __attribute__((address_space(3))) unsigned int as3_uint;
typedef __attribute__((address_space(1))) const unsigned int as1_uint;

__device__ __forceinline__ void gld_lds16(const f16* g, f16* l) {
    __builtin_amdgcn_global_load_lds((as1_uint*)g, (as3_uint*)l, 16, 0, 0);
}

// fp32 -> fp16 (hi plane only; for A-side operands)
__global__ __launch_bounds__(256) void split_hi(const float* __restrict__ x,
                                                f16* __restrict__ hi, int n4) {
    int i = blockIdx.x * 256 + threadIdx.x;
    if (i >= n4) return;
    float4 v = ((const float4*)x)[i];
    f16x4 h = {(f16)v.x, (f16)v.y, (f16)v.z, (f16)v.w};
    ((f16x4*)hi)[i] = h;
}

// fp32 -> fp16 hi + lo planes (for B-side weights)
__global__ __launch_bounds__(256) void split_hilo(const float* __restrict__ x,
                                                  f16* __restrict__ hi,
                                                  f16* __restrict__ lo, int n4) {
    int i = blockIdx.x * 256 + threadIdx.x;
    if (i >= n4) return;
    float4 v = ((const float4*)x)[i];
    float f[4] = {v.x, v.y, v.z, v.w};
    f16 h[4], l[4];
    #pragma unroll
    for (int j = 0; j < 4; ++j) {
        h[j] = (f16)f[j];
        l[j] = (f16)(f[j] - (float)h[j]);
    }
    ((f16x4*)hi)[i] = (f16x4){h[0], h[1], h[2], h[3]};
    ((f16x4*)lo)[i] = (f16x4){l[0], l[1], l[2], l[3]};
}

// C[M,N] = A[M,K] @ (Bhi+Blo)[N,K]^T, fp16 2-term split MFMA.
// 128x128 tile, BK=32, 4 waves, each wave a 64x64 quadrant of 16x16x32 MFMAs.
__global__ __launch_bounds__(256) void gemm_2t(const f16* __restrict__ A,
                                               const f16* __restrict__ Bhi,
                                               const f16* __restrict__ Blo,
                                               float* __restrict__ C,
                                               int M, int N, int K) {
    __shared__ f16 smem[3 * 128 * 32];   // A | Bhi | Blo, 24 KB
    f16* sA  = smem;
    f16* sBh = smem + 4096;
    f16* sBl = smem + 8192;

    const int t = threadIdx.x;
    const int w = t >> 6;
    const int lane = t & 63;
    const int bm = blockIdx.y * 128;
    const int bn = blockIdx.x * 128;
    const int wm = (w & 1) * 64;
    const int wn = (w >> 1) * 64;

    f32x4 acc[4][4] = {};

    const int frow = lane & 15;
    const int fk = (lane >> 4) * 8;

    // staging: thread t covers LDS row (t>>2), 8-elem chunk (t&3), two rounds
    const int row0 = t >> 2, ch0 = (t & 3) * 8;
    const size_t aoff0 = (size_t)(bm + row0) * K + ch0;
    const size_t aoff1 = (size_t)(bm + 64 + row0) * K + ch0;
    const size_t boff0 = (size_t)(bn + row0) * K + ch0;
    const size_t boff1 = (size_t)(bn + 64 + row0) * K + ch0;
    const unsigned loff0 = (w * 64) * 8;
    const unsigned loff1 = (256 + w * 64) * 8;

    // prologue: stage k0 = 0
    gld_lds16(A   + aoff0, sA  + loff0);  gld_lds16(A   + aoff1, sA  + loff1);
    gld_lds16(Bhi + boff0, sBh + loff0);  gld_lds16(Bhi + boff1, sBh + loff1);
    gld_lds16(Blo + boff0, sBl + loff0);  gld_lds16(Blo + boff1, sBl + loff1);

    for (int k0 = 0; k0 < K; k0 += 32) {
        __syncthreads();   // staging of tile k0 complete

        f16x8 a[4], bh[4], bl[4];
        #pragma unroll
        for (int i = 0; i < 4; ++i)
            a[i] = *(const f16x8*)(sA + (wm + i * 16 + frow) * 32 + fk);
        #pragma unroll
        for (int j = 0; j < 4; ++j) {
            bh[j] = *(const f16x8*)(sBh + (wn + j * 16 + frow) * 32 + fk);
            bl[j] = *(const f16x8*)(sBl + (wn + j * 16 + frow) * 32 + fk);
        }

        __syncthreads();   // all waves done reading -> safe to restage

        if (k0 + 32 < K) {
            const int kn = k0 + 32;
            gld_lds16(A   + aoff0 + kn, sA  + loff0);  gld_lds16(A   + aoff1 + kn, sA  + loff1);
            gld_lds16(Bhi + boff0 + kn, sBh + loff0);  gld_lds16(Bhi + boff1 + kn, sBh + loff1);
            gld_lds16(Blo + boff0 + kn, sBl + loff0);  gld_lds16(Blo + boff1 + kn, sBl + loff1);
        }

        #pragma unroll
        for (int i = 0; i < 4; ++i)
            #pragma unroll
            for (int j = 0; j < 4; ++j)
                acc[i][j] = __builtin_amdgcn_mfma_f32_16x16x32_f16(a[i], bh[j], acc[i][j], 0, 0, 0);
        #pragma unroll
        for (int i = 0; i < 4; ++i)
            #pragma unroll
            for (int j = 0; j < 4; ++j)
                acc[i][j] = __builtin_amdgcn_mfma_f32_16x16x32_f16(a[i], bl[j], acc[i][j], 0, 0, 0);
    }

    // epilogue: C/D layout col = lane&15, row = (lane>>4)*4 + reg
    const int rbase = bm + wm + (lane >> 4) * 4;
    const int cbase = bn + wn + (lane & 15);
    #pragma unroll
    for (int i = 0; i < 4; ++i)
        #pragma unroll
        for (int j = 0; j < 4; ++j)
            #pragma unroll
            for (int r = 0; r < 4; ++r)
                C[(size_t)(rbase + i * 16 + r) * N + cbase + j * 16] = acc[i][j][r];
}

// One wave = one query row x 4 heads. lane = 16*hh + s; lane owns d in [4s, 4s+4).
// Dot: 4 FMAs + 4-step 16-lane butterfly. PV: no cross-lane reduce needed.
__global__ __launch_bounds__(256) void attn_kernel(const float* __restrict__ qh,   // (B*LQ, 1024) fp32
                                                   const float* __restrict__ kvp,  // (B*LKV, 2048): K|V fp32
                                                   const int* __restrict__ seg_id, // (B*LQ)
                                                   f16* __restrict__ attn_hi) {    // (B*LQ, 1024) fp16
    const int wid = blockIdx.x * 4 + (threadIdx.x >> 6);
    const int lane = threadIdx.x & 63;
    const int row = wid >> 2;          // b*LQ + qi
    const int hg  = wid & 3;
    const int hh = lane >> 4;
    const int s  = lane & 15;
    const int head = hg * 4 + hh;
    const int b = row >> 12;           // LQ = 4096
    const int seg = seg_id[row];
    const int dbase = head * HDIM + 4 * s;

    const float4 q4 = *(const float4*)(qh + (size_t)row * D_ATTN + dbase);
    const float* kvb = kvp + (size_t)b * LKV_C * (2 * D_ATTN);

    float sc[KW];
    #pragma unroll
    for (int w = 0; w < KW; ++w) {
        const int j = seg - w;
        float p = 0.f;
        if (j >= 0) {
            const float4 k4 = *(const float4*)(kvb + (size_t)j * (2 * D_ATTN) + dbase);
            p = q4.x * k4.x + q4.y * k4.y + q4.z * k4.z + q4.w * k4.w;
        }
        p += __shfl_xor(p, 1);
        p += __shfl_xor(p, 2);
        p += __shfl_xor(p, 4);
        p += __shfl_xor(p, 8);
        sc[w] = (j >= 0) ? p * ATT_SCALE : -1e30f;
    }

    const float m = fmaxf(fmaxf(sc[0], sc[1]), fmaxf(sc[2], sc[3]));
    float e[KW], sum = 0.f;
    #pragma unroll
    for (int w = 0; w < KW; ++w) {
        e[w] = __expf(sc[w] - m);   // invalid windows: exp(-1e30) == 0
        sum += e[w];
    }
    const float inv = 1.f / sum;

    float4 o = make_float4(0.f, 0.f, 0.f, 0.f);
    #pragma unroll
    for (int w = 0; w < KW; ++w) {
        const int j = seg - w;
        if (j >= 0) {
            const float4 v4 = *(const float4*)(kvb + (size_t)j * (2 * D_ATTN) + D_ATTN + dbase);
            const float c = e[w] * inv;
            o.x = fmaf(c, v4.x, o.x);
            o.y = fmaf(c, v4.y, o.y);
            o.z = fmaf(c, v4.z, o.z);
            o.w = fmaf(c, v4.w, o.w);
        }
    }

    *(f16x4*)(attn_hi + (size_t)row * D_ATTN + dbase) =
        (f16x4){(f16)o.x, (f16)o.y, (f16)o.z, (f16)o.w};
}

extern "C" void kernel_launch(void* const* d_in, const int* in_sizes, int n_in,
                              void* d_out, int out_size, void* d_ws, size_t ws_size,
                              hipStream_t stream) {
    const float* q      = (const float*)d_in[0]; // (4,4096,1024)
    const float* kv_src = (const float*)d_in[1]; // (4,512,1024)
    const int*   seg    = (const int*)  d_in[2]; // (4,4096)
    const float* Wq     = (const float*)d_in[3]; // (1024,1024)
    const float* Wkv    = (const float*)d_in[4]; // (2048,1024)
    const float* Wo     = (const float*)d_in[5]; // (1024,1024)
    float* out = (float*)d_out;

    const int M  = B_C * LQ_C;    // 16384
    const int Mk = B_C * LKV_C;   // 2048

    // workspace layout (~68 MB)
    f16* q_hi   = (f16*)d_ws;                       // 32 MB
    f16* kvs_hi = q_hi   + (size_t)M * D_ATTN;      // 4 MB
    f16* Wq_hi  = kvs_hi + (size_t)Mk * 1024;       // 2 MB
    f16* Wq_lo  = Wq_hi  + 1024 * 1024;             // 2 MB
    f16* Wkv_hi = Wq_lo  + 1024 * 1024;             // 4 MB
    f16* Wkv_lo = Wkv_hi + 2048 * 1024;             // 4 MB
    f16* Wo_hi  = Wkv_lo + 2048 * 1024;             // 2 MB
    f16* Wo_lo  = Wo_hi  + 1024 * 1024;             // 2 MB
    float* kvp  = (float*)(Wo_lo + 1024 * 1024);    // 16 MB
    f16* attn_hi = q_hi;            // alias: q_hi dead after GEMM1
    float* qh = (float*)d_out;      // qh parked in d_out, overwritten by GEMM3

    // 1. splits
    split_hi  <<<(M * D_ATTN) / 1024, 256, 0, stream>>>(q, q_hi, (M * D_ATTN) / 4);
    split_hi  <<<(Mk * 1024) / 1024, 256, 0, stream>>>(kv_src, kvs_hi, (Mk * 1024) / 4);
    split_hilo<<<(1024 * 1024) / 1024, 256, 0, stream>>>(Wq, Wq_hi, Wq_lo, (1024 * 1024) / 4);
    split_hilo<<<(2048 * 1024) / 1024, 256, 0, stream>>>(Wkv, Wkv_hi, Wkv_lo, (2048 * 1024) / 4);
    split_hilo<<<(1024 * 1024) / 1024, 256, 0, stream>>>(Wo, Wo_hi, Wo_lo, (1024 * 1024) / 4);

    // 2. qh = q @ Wq^T  (into d_out)
    gemm_2t<<<dim3(1024 / 128, M / 128), 256, 0, stream>>>(q_hi, Wq_hi, Wq_lo, qh, M, 1024, 1024);
    // 3. kvp = kv_src @ Wkv^T
    gemm_2t<<<dim3(2048 / 128, Mk / 128), 256, 0, stream>>>(kvs_hi, Wkv_hi, Wkv_lo, kvp, Mk, 2048, 1024);
    // 4. windowed attention -> fp16 attn (aliases q_hi)
    attn_kernel<<<(M * NH) / 16, 256, 0, stream>>>(qh, kvp, seg, attn_hi);
    // 5. out = attn @ Wo^T  (overwrites d_out)
    gemm_2t<<<dim3(1024 / 128, M / 128), 256, 0, stream>>>(attn_hi, Wo_hi, Wo_lo, out, M, 1024, 1024);
}

// Round 4
// 316.423 us; speedup vs baseline: 5.2179x; 1.1669x over previous
//
#include <hip/hip_runtime.h>
#include <math.h>

#define NH 16
#define HDIM 64
#define D_ATTN 1024
#define KW 4
#define ATT_SCALE 0.125f
#define LKV_C 512
#define LQ_C 4096
#define B_C 4

typedef _Float16 f16;
typedef _Float16 f16x8 __attribute__((ext_vector_type(8)));
typedef _Float16 f16x4 __attribute__((ext_vector_type(4)));
typedef float f32x4 __attribute__((ext_vector_type(4)));

typedef __attribute__((address_space(3))) unsigned int as3_uint;
typedef __attribute__((address_space(1))) const unsigned int as1_uint;

__device__ __forceinline__ void gld_lds16(const f16* g, f16* l) {
    __builtin_amdgcn_global_load_lds((as1_uint*)g, (as3_uint*)l, 16, 0, 0);
}

// fp32 -> fp16
__global__ __launch_bounds__(256) void split_hi(const float* __restrict__ x,
                                                f16* __restrict__ hi, int n4) {
    int i = blockIdx.x * 256 + threadIdx.x;
    if (i >= n4) return;
    float4 v = ((const float4*)x)[i];
    ((f16x4*)hi)[i] = (f16x4){(f16)v.x, (f16)v.y, (f16)v.z, (f16)v.w};
}

// C[M,N] = A[M,K] @ B[N,K]^T, pure fp16 MFMA, fp32 accumulate.
// 128x128 tile, BK=32, 4 waves, each wave a 64x64 quadrant of 16x16x32 MFMAs.
// LDS k-chunk XOR swizzle: chunk c of row r stored at pos c ^ ((r>>1)&3).
__global__ __launch_bounds__(256) void gemm_f16(const f16* __restrict__ A,
                                                const f16* __restrict__ B,
                                                float* __restrict__ C,
                                                int M, int N, int K) {
    __shared__ f16 smem[2 * 128 * 32];   // A | B, 16 KB
    f16* sA = smem;
    f16* sB = smem + 4096;

    const int t = threadIdx.x;
    const int w = t >> 6;
    const int lane = t & 63;
    const int bm = blockIdx.y * 128;
    const int bn = blockIdx.x * 128;
    const int wm = (w & 1) * 64;
    const int wn = (w >> 1) * 64;

    f32x4 acc[4][4] = {};

    const int frow = lane & 15;
    const int fchunk = lane >> 4;        // k-chunk 0..3 (8 f16 each)

    // staging: thread t -> slot row (t>>2); swizzled source chunk
    const int srow = t >> 2;
    const int chunk = (t & 3) ^ ((t >> 3) & 3);     // == (t&3) ^ ((srow>>1)&3)
    const size_t aoff0 = (size_t)(bm + srow) * K + chunk * 8;
    const size_t aoff1 = (size_t)(bm + 64 + srow) * K + chunk * 8;
    const size_t boff0 = (size_t)(bn + srow) * K + chunk * 8;
    const size_t boff1 = (size_t)(bn + 64 + srow) * K + chunk * 8;
    const unsigned loff0 = (w * 64) * 8;
    const unsigned loff1 = (256 + w * 64) * 8;

    // prologue: stage k0 = 0
    gld_lds16(A + aoff0, sA + loff0);  gld_lds16(A + aoff1, sA + loff1);
    gld_lds16(B + boff0, sB + loff0);  gld_lds16(B + boff1, sB + loff1);

    for (int k0 = 0; k0 < K; k0 += 32) {
        __syncthreads();   // staging of tile k0 complete

        f16x8 a[4], b[4];
        #pragma unroll
        for (int i = 0; i < 4; ++i) {
            const int r = wm + i * 16 + frow;
            a[i] = *(const f16x8*)(sA + r * 32 + (fchunk ^ ((r >> 1) & 3)) * 8);
        }
        #pragma unroll
        for (int j = 0; j < 4; ++j) {
            const int r = wn + j * 16 + frow;
            b[j] = *(const f16x8*)(sB + r * 32 + (fchunk ^ ((r >> 1) & 3)) * 8);
        }

        __syncthreads();   // all waves done reading -> safe to restage

        if (k0 + 32 < K) {
            const int kn = k0 + 32;
            gld_lds16(A + aoff0 + kn, sA + loff0);  gld_lds16(A + aoff1 + kn, sA + loff1);
            gld_lds16(B + boff0 + kn, sB + loff0);  gld_lds16(B + boff1 + kn, sB + loff1);
        }

        #pragma unroll
        for (int i = 0; i < 4; ++i)
            #pragma unroll
            for (int j = 0; j < 4; ++j)
                acc[i][j] = __builtin_amdgcn_mfma_f32_16x16x32_f16(a[i], b[j], acc[i][j], 0, 0, 0);
    }

    // epilogue: C/D layout col = lane&15, row = (lane>>4)*4 + reg
    const int rbase = bm + wm + (lane >> 4) * 4;
    const int cbase = bn + wn + (lane & 15);
    #pragma unroll
    for (int i = 0; i < 4; ++i)
        #pragma unroll
        for (int j = 0; j < 4; ++j)
            #pragma unroll
            for (int r = 0; r < 4; ++r)
                C[(size_t)(rbase + i * 16 + r) * N + cbase + j * 16] = acc[i][j][r];
}

// One wave = one query row x 4 heads. lane = 16*hh + s; lane owns d in [4s, 4s+4).
__global__ __launch_bounds__(256) void attn_kernel(const float* __restrict__ qh,   // (B*LQ, 1024) fp32
                                                   const float* __restrict__ kvp,  // (B*LKV, 2048): K|V fp32
                                                   const int* __restrict__ seg_id, // (B*LQ)
                                                   f16* __restrict__ attn_o) {     // (B*LQ, 1024) fp16
    const int wid = blockIdx.x * 4 + (threadIdx.x >> 6);
    const int lane = threadIdx.x & 63;
    const int row = wid >> 2;          // b*LQ + qi
    const int hg  = wid & 3;
    const int hh = lane >> 4;
    const int s  = lane & 15;
    const int head = hg * 4 + hh;
    const int b = row >> 12;           // LQ = 4096
    const int seg = seg_id[row];
    const int dbase = head * HDIM + 4 * s;

    const float4 q4 = *(const float4*)(qh + (size_t)row * D_ATTN + dbase);
    const float* kvb = kvp + (size_t)b * LKV_C * (2 * D_ATTN);

    float sc[KW];
    #pragma unroll
    for (int w = 0; w < KW; ++w) {
        const int j = seg - w;
        float p = 0.f;
        if (j >= 0) {
            const float4 k4 = *(const float4*)(kvb + (size_t)j * (2 * D_ATTN) + dbase);
            p = q4.x * k4.x + q4.y * k4.y + q4.z * k4.z + q4.w * k4.w;
        }
        p += __shfl_xor(p, 1);
        p += __shfl_xor(p, 2);
        p += __shfl_xor(p, 4);
        p += __shfl_xor(p, 8);
        sc[w] = (j >= 0) ? p * ATT_SCALE : -1e30f;
    }

    const float m = fmaxf(fmaxf(sc[0], sc[1]), fmaxf(sc[2], sc[3]));
    float e[KW], sum = 0.f;
    #pragma unroll
    for (int w = 0; w < KW; ++w) {
        e[w] = __expf(sc[w] - m);
        sum += e[w];
    }
    const float inv = 1.f / sum;

    float4 o = make_float4(0.f, 0.f, 0.f, 0.f);
    #pragma unroll
    for (int w = 0; w < KW; ++w) {
        const int j = seg - w;
        if (j >= 0) {
            const float4 v4 = *(const float4*)(kvb + (size_t)j * (2 * D_ATTN) + D_ATTN + dbase);
            const float c = e[w] * inv;
            o.x = fmaf(c, v4.x, o.x);
            o.y = fmaf(c, v4.y, o.y);
            o.z = fmaf(c, v4.z, o.z);
            o.w = fmaf(c, v4.w, o.w);
        }
    }

    *(f16x4*)(attn_o + (size_t)row * D_ATTN + dbase) =
        (f16x4){(f16)o.x, (f16)o.y, (f16)o.z, (f16)o.w};
}

extern "C" void kernel_launch(void* const* d_in, const int* in_sizes, int n_in,
                              void* d_out, int out_size, void* d_ws, size_t ws_size,
                              hipStream_t stream) {
    const float* q      = (const float*)d_in[0]; // (4,4096,1024)
    const float* kv_src = (const float*)d_in[1]; // (4,512,1024)
    const int*   seg    = (const int*)  d_in[2]; // (4,4096)
    const float* Wq     = (const float*)d_in[3]; // (1024,1024)
    const float* Wkv    = (const float*)d_in[4]; // (2048,1024)
    const float* Wo     = (const float*)d_in[5]; // (1024,1024)
    float* out = (float*)d_out;

    const int M  = B_C * LQ_C;    // 16384
    const int Mk = B_C * LKV_C;   // 2048

    // workspace layout (~60 MB)
    f16* q_hi   = (f16*)d_ws;                       // 32 MB
    f16* kvs_hi = q_hi   + (size_t)M * D_ATTN;      // 4 MB
    f16* Wq_hi  = kvs_hi + (size_t)Mk * 1024;       // 2 MB
    f16* Wkv_hi = Wq_hi  + 1024 * 1024;             // 4 MB
    f16* Wo_hi  = Wkv_hi + 2048 * 1024;             // 2 MB
    float* kvp  = (float*)(Wo_hi + 1024 * 1024);    // 16 MB
    f16* attn_o = q_hi;             // alias: q_hi dead after GEMM1
    float* qh = (float*)d_out;      // qh parked in d_out, overwritten by GEMM3

    // 1. fp32 -> fp16 conversions
    split_hi<<<(M * D_ATTN) / 1024, 256, 0, stream>>>(q, q_hi, (M * D_ATTN) / 4);
    split_hi<<<(Mk * 1024) / 1024, 256, 0, stream>>>(kv_src, kvs_hi, (Mk * 1024) / 4);
    split_hi<<<(1024 * 1024) / 1024, 256, 0, stream>>>(Wq, Wq_hi, (1024 * 1024) / 4);
    split_hi<<<(2048 * 1024) / 1024, 256, 0, stream>>>(Wkv, Wkv_hi, (2048 * 1024) / 4);
    split_hi<<<(1024 * 1024) / 1024, 256, 0, stream>>>(Wo, Wo_hi, (1024 * 1024) / 4);

    // 2. qh = q @ Wq^T  (into d_out)
    gemm_f16<<<dim3(1024 / 128, M / 128), 256, 0, stream>>>(q_hi, Wq_hi, qh, M, 1024, 1024);
    // 3. kvp = kv_src @ Wkv^T
    gemm_f16<<<dim3(2048 / 128, Mk / 128), 256, 0, stream>>>(kvs_hi, Wkv_hi, kvp, Mk, 2048, 1024);
    // 4. windowed attention -> fp16 attn (aliases q_hi)
    attn_kernel<<<(M * NH) / 16, 256, 0, stream>>>(qh, kvp, seg, attn_o);
    // 5. out = attn @ Wo^T  (overwrites d_out)
    gemm_f16<<<dim3(1024 / 128, M / 128), 256, 0, stream>>>(attn_o, Wo_hi, out, M, 1024, 1024);
}